// Round 17
// baseline (149.115 us; speedup 1.0000x reference)
//
#include <hip/hip_runtime.h>

typedef __attribute__((ext_vector_type(8))) short short8;
typedef _Float16 half8 __attribute__((ext_vector_type(8)));
typedef __attribute__((ext_vector_type(4))) float f32x4;
typedef __attribute__((ext_vector_type(4))) unsigned int uint4v;
typedef __attribute__((ext_vector_type(2))) unsigned int uint2v;

#define B_   8
#define LX_  2048
#define LY_  2048
#define D_   256
#define NROW (B_ * LX_)   // 16384

__device__ __forceinline__ unsigned short f2bf(float f) {
  unsigned u = __builtin_bit_cast(unsigned, f);
  u += 0x7FFF + ((u >> 16) & 1);          // RNE truncate (inputs are finite)
  return (unsigned short)(u >> 16);
}
__device__ __forceinline__ float bf2f(unsigned short h) {
  unsigned u = ((unsigned)h) << 16;
  return __builtin_bit_cast(float, u);
}

// ---------------- prep: blocks 0..7 mask scan; blocks 8..39 W split ---
__global__ __launch_bounds__(256) void prep_kernel(
    const float* __restrict__ W, unsigned short* __restrict__ Whi,
    unsigned short* __restrict__ Wlo,
    const int* __restrict__ MASK, int* __restrict__ CIDX, int* __restrict__ Lc) {
  int t = threadIdx.x;
  if (blockIdx.x >= 8) {
    int base = (blockIdx.x - 8) * 2048 + t * 8;
    f32x4 f0 = *(const f32x4*)(W + base);
    f32x4 f1 = *(const f32x4*)(W + base + 4);
    float v[8] = {f0[0], f0[1], f0[2], f0[3], f1[0], f1[1], f1[2], f1[3]};
    unsigned short h[8], l[8];
    for (int j = 0; j < 8; ++j) {
      h[j] = f2bf(v[j]);
      l[j] = f2bf(v[j] - bf2f(h[j]));
    }
    uint4v vh = {(unsigned)h[0] | ((unsigned)h[1] << 16), (unsigned)h[2] | ((unsigned)h[3] << 16),
                 (unsigned)h[4] | ((unsigned)h[5] << 16), (unsigned)h[6] | ((unsigned)h[7] << 16)};
    uint4v vl = {(unsigned)l[0] | ((unsigned)l[1] << 16), (unsigned)l[2] | ((unsigned)l[3] << 16),
                 (unsigned)l[4] | ((unsigned)l[5] << 16), (unsigned)l[6] | ((unsigned)l[7] << 16)};
    *(uint4v*)(Whi + base) = vh;
    *(uint4v*)(Wlo + base) = vl;
    return;
  }
  __shared__ int s[256];
  int b = blockIdx.x;
  int f[8];
  int cnt = 0;
  for (int k = 0; k < 8; ++k) {
    f[k] = (MASK[b * 2048 + t * 8 + k] == 0) ? 1 : 0;
    cnt += f[k];
  }
  s[t] = cnt;
  __syncthreads();
  for (int off = 1; off < 256; off <<= 1) {
    int v = (t >= off) ? s[t - off] : 0;
    __syncthreads();
    s[t] += v;
    __syncthreads();
  }
  if (t == 255) Lc[b] = s[255];
  int off = s[t] - cnt;
  for (int k = 0; k < 8; ++k) {
    int j = t * 8 + k;
    if (f[k]) CIDX[b * 2048 + (off++)] = j;
  }
}

// ---------------- fused: blocks 0..511 proj ; 512..1535 gatherT -------
// (256,3): 3 blocks/CU — r16-verified (+1 us, no spill).
__global__ __launch_bounds__(256, 3) void projgather_kernel(
    const float* __restrict__ X, const float* __restrict__ Y,
    const float* __restrict__ bias,
    const unsigned short* __restrict__ Whi, const unsigned short* __restrict__ Wlo,
    const int* __restrict__ CIDX, const int* __restrict__ Lc,
    _Float16* __restrict__ XP, _Float16* __restrict__ YPc,
    _Float16* __restrict__ YTc) {
  __shared__ __align__(16) unsigned char smem[51200];
  int t = threadIdx.x;

  if (blockIdx.x >= 512) {
    // ---------------- gatherT ----------------
    _Float16 (*tile)[72] = (_Float16(*)[72])smem;
    int id = blockIdx.x - 512;
    int db = id & 3, nb = (id >> 2) & 31, b = id >> 7;
    int lc = Lc[b];
    int end = (lc + 31) & ~31;
    if (nb * 64 >= end) return;
    int nl = t >> 2, ds = t & 3;
    int j = nb * 64 + nl;
    int idx = (j < lc) ? CIDX[b * 2048 + j] : 0;
    const float* src = Y + (size_t)(b * LY_ + idx) * D_ + db * 64 + ds * 16;
    for (int i = 0; i < 4; ++i) {
      f32x4 f = *(const f32x4*)(src + i * 4);
      for (int k = 0; k < 4; ++k) tile[ds * 16 + i * 4 + k][nl] = (_Float16)f[k];
    }
    __syncthreads();
    int dl = t >> 2, nsub = t & 3;
    uint4v v0 = *(const uint4v*)&tile[dl][nsub * 16];
    uint4v v1 = *(const uint4v*)&tile[dl][nsub * 16 + 8];
    _Float16* dst = YTc + (size_t)(b * D_ + db * 64 + dl) * LY_ + nb * 64 + nsub * 16;
    *(uint4v*)(dst) = v0;
    *(uint4v*)(dst + 8) = v1;
    return;
  }

  // ---------------- proj ----------------
  unsigned short (*Ah)[40] = (unsigned short(*)[40])(smem);           // 5120
  unsigned short (*Al)[40] = (unsigned short(*)[40])(smem + 5120);    // 5120
  unsigned short (*Bh)[40] = (unsigned short(*)[40])(smem + 10240);   // 20480
  unsigned short (*Bl)[40] = (unsigned short(*)[40])(smem + 30720);   // 20480

  int lane = t & 63, wave = t >> 6;
  int q = lane >> 4, n15 = lane & 15;
  int arow = t >> 2, aseg = t & 3;
  int erow = t >> 2, ec = t & 3;

  bool isX = blockIdx.x < 256;
  int m0 = 0, b = 0, slot0 = 0, lcb = 0;
  const float* arow_ptr;
  if (isX) {
    m0 = blockIdx.x * 64;
    arow_ptr = X + (size_t)(m0 + arow) * D_;
  } else {
    int id = blockIdx.x - 256;
    b = id >> 5;
    int rb = id & 31;
    lcb = Lc[b];
    slot0 = rb * 64;
    if (slot0 >= lcb) return;          // uniform exit, no barriers crossed
    int sl = slot0 + arow;
    int grow = (sl < lcb) ? CIDX[b * 2048 + sl] : 0;
    arow_ptr = Y + (size_t)(b * 2048 + grow) * D_;
  }

  f32x4 acc[4][4];
  for (int mt = 0; mt < 4; ++mt)
    for (int nt = 0; nt < 4; ++nt) acc[mt][nt] = (f32x4){0.f, 0.f, 0.f, 0.f};

  f32x4 pa[2];
  uint4v pbh[4], pbl[4];
#define PROJ_PF(kc)                                                            \
  {                                                                            \
    for (int i = 0; i < 2; ++i)                                                \
      pa[i] = *(const f32x4*)(arow_ptr + (kc) * 32 + (aseg + i * 4) * 4);      \
    for (int p = 0; p < 4; ++p) {                                              \
      int e = p * 64 + erow;                                                   \
      pbh[p] = *(const uint4v*)(Whi + (size_t)e * D_ + (kc) * 32 + ec * 8);    \
      pbl[p] = *(const uint4v*)(Wlo + (size_t)e * D_ + (kc) * 32 + ec * 8);    \
    }                                                                          \
  }

  PROJ_PF(0);

  for (int kc = 0; kc < 8; ++kc) {
    __syncthreads();
    for (int i = 0; i < 2; ++i) {
      int seg = aseg + i * 4;
      f32x4 f = pa[i];
      unsigned short h[4], l[4];
      for (int j = 0; j < 4; ++j) {
        h[j] = f2bf(f[j]);
        l[j] = f2bf(f[j] - bf2f(h[j]));
      }
      uint2v vh = {(unsigned)h[0] | ((unsigned)h[1] << 16),
                   (unsigned)h[2] | ((unsigned)h[3] << 16)};
      uint2v vl = {(unsigned)l[0] | ((unsigned)l[1] << 16),
                   (unsigned)l[2] | ((unsigned)l[3] << 16)};
      *(uint2v*)&Ah[arow][seg * 4] = vh;
      *(uint2v*)&Al[arow][seg * 4] = vl;
    }
    for (int p = 0; p < 4; ++p) {
      int e = p * 64 + erow;
      *(uint4v*)&Bh[e][ec * 8] = pbh[p];
      *(uint4v*)&Bl[e][ec * 8] = pbl[p];
    }
    if (kc < 7) PROJ_PF(kc + 1);
    __syncthreads();

    short8 afh[4], afl[4], bfh[4], bfl[4];
    for (int mt = 0; mt < 4; ++mt) {
      afh[mt] = *(const short8*)&Ah[mt * 16 + n15][q * 8];
      afl[mt] = *(const short8*)&Al[mt * 16 + n15][q * 8];
    }
    for (int nt = 0; nt < 4; ++nt) {
      bfh[nt] = *(const short8*)&Bh[wave * 64 + nt * 16 + n15][q * 8];
      bfl[nt] = *(const short8*)&Bl[wave * 64 + nt * 16 + n15][q * 8];
    }
    for (int mt = 0; mt < 4; ++mt)
      for (int nt = 0; nt < 4; ++nt) {
        acc[mt][nt] = __builtin_amdgcn_mfma_f32_16x16x32_bf16(afh[mt], bfh[nt], acc[mt][nt], 0, 0, 0);
        acc[mt][nt] = __builtin_amdgcn_mfma_f32_16x16x32_bf16(afl[mt], bfh[nt], acc[mt][nt], 0, 0, 0);
        acc[mt][nt] = __builtin_amdgcn_mfma_f32_16x16x32_bf16(afh[mt], bfl[nt], acc[mt][nt], 0, 0, 0);
      }
  }
#undef PROJ_PF

  // ---- epilogue: bias+relu -> LDS bounce -> coalesced uint4 stores
  __syncthreads();                       // all waves done reading Bh/Bl
  _Float16 (*epi)[264] = (_Float16(*)[264])smem;   // 64 x 264 fp16 = 33792 B
  for (int nt = 0; nt < 4; ++nt) {
    int e = wave * 64 + nt * 16 + n15;
    float bv = bias[e];
    for (int mt = 0; mt < 4; ++mt)
      for (int r = 0; r < 4; ++r) {
        float v = acc[mt][nt][r] + bv;
        v = v > 0.f ? v : 0.f;
        epi[mt * 16 + q * 4 + r][e] = (_Float16)v;
      }
  }
  __syncthreads();
  int row = t >> 2, seg = t & 3;
  bool valid = isX || (slot0 + row < lcb);
  if (valid) {
    _Float16* drp = isX ? (XP + (size_t)(m0 + row) * D_)
                        : (YPc + (size_t)(b * 2048 + slot0 + row) * D_);
    for (int k = 0; k < 8; ++k) {
      uint4v v = *(const uint4v*)&epi[row][seg * 64 + k * 8];
      *(uint4v*)(drp + seg * 64 + k * 8) = v;
    }
  }
}

// ---------------- flash + in-block merge, 64-j tiles ------------------
// r15/r16-verified structure. NEW (r17): T13 defer-max RESCALE_THRESHOLD
// = 8 — skip the O-rescale when the tile max grows by <= 8 (per-row
// uniform decision; P bounded by e^8, fp16-safe; lacc/oacc fp32).
// Group-1's parked O is now fp32 in LDS (e^8-scaled O can exceed fp16).
__global__ __launch_bounds__(512, 2) void flashout_kernel(
    const _Float16* __restrict__ XP, const _Float16* __restrict__ YPc,
    const _Float16* __restrict__ YTc, const int* __restrict__ Lc,
    float* __restrict__ OUT) {
  __shared__ __align__(16) _Float16 yp_t[2][64][264];   // 67584
  __shared__ __align__(16) _Float16 yT_t[2][256][64];   // 65536, chunk^row
  __shared__ __align__(16) _Float16 pbuf[8][16][72];    // 18432

  int t = threadIdx.x;                 // 0..511
  int lane = t & 63, wave = t >> 6;    // wave 0..7
  int g = wave >> 2;                   // tile-half group 0/1
  int wv = wave & 3;                   // wave-in-group
  int tl = t & 255;                    // thread-in-group
  int q = lane >> 4, n15 = lane & 15;
  int wg = (int)blockIdx.x;            // 0..255
  int swz = (wg & 7) * 32 + (wg >> 3); // batch<->XCD, bijective on [0,256)
  int xb = swz & 31;
  int b = swz >> 5;
  int row0 = xb * 64 + wv * 16;

  int lc = Lc[b];
  int T  = (lc + 63) >> 6;             // 64-j tiles
  int tstart = (T * g) >> 1;
  int tend   = (T * (g + 1)) >> 1;
  int nit    = T - (T >> 1);           // ceil(T/2) >= both group counts

  half8 a[8];
  const _Float16* xrow = XP + (size_t)(b * LX_ + row0 + n15) * D_ + q * 8;
  for (int kk = 0; kk < 8; ++kk) a[kk] = *(const half8*)(xrow + kk * 32);

  float m_r[4];
  for (int r = 0; r < 4; ++r) m_r[r] = -1e30f;
  f32x4 lacc = {0.f, 0.f, 0.f, 0.f};
  f32x4 oacc[16];
  for (int dt = 0; dt < 16; ++dt) oacc[dt] = (f32x4){0.f, 0.f, 0.f, 0.f};

  const _Float16* ypb = YPc + (size_t)b * LY_ * D_;
  const _Float16* yTb = YTc + (size_t)b * D_ * LY_;

  uint4v pr[16];
#define PREFETCH(tt)                                                          \
  {                                                                           \
    int y0p = (tt) * 64;                                                      \
    for (int i = 0; i < 8; ++i) {                                             \
      int c = tl + i * 256;                                                   \
      pr[i] = *(const uint4v*)(ypb + (size_t)(y0p + (c >> 5)) * D_ + (c & 31) * 8); \
    }                                                                         \
    for (int i = 0; i < 8; ++i) {                                             \
      int c = tl + i * 256;                                                   \
      pr[8 + i] = *(const uint4v*)(yTb + (size_t)(c >> 3) * LY_ + y0p + (c & 7) * 8); \
    }                                                                         \
  }

  if (tstart < tend) PREFETCH(tstart);

  for (int it = 0; it < nit; ++it) {
    int tt = tstart + it;
    bool val = tt < tend;
    int y0 = tt * 64;
    __syncthreads();   // A: all waves done reading previous tile
    if (val) {
      for (int i = 0; i < 8; ++i) {
        int c = tl + i * 256;
        *(uint4v*)&yp_t[g][c >> 5][(c & 31) * 8] = pr[i];
      }
      for (int i = 0; i < 8; ++i) {
        int c = tl + i * 256;
        int rT = c >> 3, pc = (c & 7) ^ (rT & 7);     // XOR-swizzled chunk
        *(uint4v*)&yT_t[g][rT][pc * 8] = pr[8 + i];
      }
      if (tt + 1 < tend) PREFETCH(tt + 1);
    }
    __syncthreads();   // B: tile staged
    if (!val) continue;   // barriers done; compute section has none

    f32x4 S0 = {0.f, 0.f, 0.f, 0.f}, S1 = {0.f, 0.f, 0.f, 0.f};
    f32x4 S2 = {0.f, 0.f, 0.f, 0.f}, S3 = {0.f, 0.f, 0.f, 0.f};
    for (int kk = 0; kk < 8; ++kk) {
      half8 b0 = *(const half8*)&yp_t[g][n15][kk * 32 + q * 8];
      half8 b1 = *(const half8*)&yp_t[g][16 + n15][kk * 32 + q * 8];
      half8 b2 = *(const half8*)&yp_t[g][32 + n15][kk * 32 + q * 8];
      half8 b3 = *(const half8*)&yp_t[g][48 + n15][kk * 32 + q * 8];
      S0 = __builtin_amdgcn_mfma_f32_16x16x32_f16(a[kk], b0, S0, 0, 0, 0);
      S1 = __builtin_amdgcn_mfma_f32_16x16x32_f16(a[kk], b1, S1, 0, 0, 0);
      S2 = __builtin_amdgcn_mfma_f32_16x16x32_f16(a[kk], b2, S2, 0, 0, 0);
      S3 = __builtin_amdgcn_mfma_f32_16x16x32_f16(a[kk], b3, S3, 0, 0, 0);
    }
    bool mk0 = (y0 + n15) >= lc;
    bool mk1 = (y0 + 16 + n15) >= lc;
    bool mk2 = (y0 + 32 + n15) >= lc;
    bool mk3 = (y0 + 48 + n15) >= lc;

    f32x4 alv;
    bool need = false;
#pragma unroll
    for (int r = 0; r < 4; ++r) {
      float s0 = mk0 ? -1e30f : S0[r];
      float s1 = mk1 ? -1e30f : S1[r];
      float s2 = mk2 ? -1e30f : S2[r];
      float s3 = mk3 ? -1e30f : S3[r];
      float tm = fmaxf(fmaxf(s0, s1), fmaxf(s2, s3));
      tm = fmaxf(tm, __shfl_xor(tm, 1));
      tm = fmaxf(tm, __shfl_xor(tm, 2));
      tm = fmaxf(tm, __shfl_xor(tm, 4));
      tm = fmaxf(tm, __shfl_xor(tm, 8));
      // T13 defer-max: keep old max while growth <= 8 (P bounded by e^8)
      float mn, al;
      if (tm - m_r[r] <= 8.0f) {       // uniform per row (tm shfl-reduced)
        mn = m_r[r];
        al = 1.0f;
      } else {
        mn = tm;                        // tm > m_r + 8  =>  new max
        al = __expf(m_r[r] - mn);
        m_r[r] = mn;
      }
      float p0 = __expf(s0 - mn);
      float p1 = __expf(s1 - mn);
      float p2 = __expf(s2 - mn);
      float p3 = __expf(s3 - mn);
      pbuf[wave][q * 4 + r][n15]      = (_Float16)p0;
      pbuf[wave][q * 4 + r][16 + n15] = (_Float16)p1;
      pbuf[wave][q * 4 + r][32 + n15] = (_Float16)p2;
      pbuf[wave][q * 4 + r][48 + n15] = (_Float16)p3;
      lacc[r] = lacc[r] * al + (p0 + p1) + (p2 + p3);
      alv[r] = al;
      need = need || (al != 1.0f);
    }
    if (__ballot(need)) {
      for (int dt = 0; dt < 16; ++dt)
        for (int r = 0; r < 4; ++r) oacc[dt][r] *= alv[r];
    }
    half8 pa0 = *(const half8*)&pbuf[wave][n15][q * 8];
    half8 pa1 = *(const half8*)&pbuf[wave][n15][32 + q * 8];
    for (int dt = 0; dt < 16; ++dt) {
      int rT = dt * 16 + n15, x = rT & 7;
      half8 bb0 = *(const half8*)&yT_t[g][rT][(q ^ x) * 8];
      half8 bb1 = *(const half8*)&yT_t[g][rT][((4 + q) ^ x) * 8];
      oacc[dt] = __builtin_amdgcn_mfma_f32_16x16x32_f16(pa0, bb0, oacc[dt], 0, 0, 0);
      oacc[dt] = __builtin_amdgcn_mfma_f32_16x16x32_f16(pa1, bb1, oacc[dt], 0, 0, 0);
    }
  }
#undef PREFETCH

  // reduce per-lane partial l across the 16-lane column group
  for (int r = 0; r < 4; ++r) {
    float v = lacc[r];
    v += __shfl_xor(v, 1);
    v += __shfl_xor(v, 2);
    v += __shfl_xor(v, 4);
    v += __shfl_xor(v, 8);
    lacc[r] = v;
  }

  // ---- in-block merge of the two tile-halves --------------------------
  __syncthreads();   // all staging reads done; LDS reusable
  float (*Obuf)[256] = (float(*)[256])&yp_t[0][0][0];        // 65536 B (fp32!)
  float (*ml)[2] = (float(*)[2])&yT_t[0][0][0];              //   512 B
  if (g == 1) {
    for (int dt = 0; dt < 16; ++dt)
      for (int r = 0; r < 4; ++r)
        Obuf[wv * 16 + q * 4 + r][dt * 16 + n15] = oacc[dt][r];
    if (n15 == 0)
      for (int r = 0; r < 4; ++r) {
        ml[wv * 16 + q * 4 + r][0] = m_r[r];
        ml[wv * 16 + q * 4 + r][1] = lacc[r];
      }
  }
  __syncthreads();
  if (g == 0) {
    for (int r = 0; r < 4; ++r) {
      int rl = wv * 16 + q * 4 + r;
      float m1 = ml[rl][0], l1 = ml[rl][1];
      float m0 = m_r[r], l0 = lacc[r];
      float mm = fmaxf(m0, m1);
      float w0 = __expf(m0 - mm), w1 = __expf(m1 - mm);
      float inv = 1.0f / (l0 * w0 + l1 * w1);
      float* orow = OUT + (size_t)(b * LX_ + xb * 64 + rl) * D_;
      for (int dt = 0; dt < 16; ++dt) {
        float o1 = Obuf[rl][dt * 16 + n15];
        orow[dt * 16 + n15] = (oacc[dt][r] * w0 + o1 * w1) * inv;
      }
    }
  }
}

extern "C" void kernel_launch(void* const* d_in, const int* in_sizes, int n_in,
                              void* d_out, int out_size, void* d_ws, size_t ws_size,
                              hipStream_t stream) {
  const float* x     = (const float*)d_in[0];  // [8,2048,256]
  const float* y     = (const float*)d_in[1];  // [8,2048,256]
  const int*   ymask = (const int*)  d_in[2];  // [8,2048]
  const float* W     = (const float*)d_in[3];  // [256,256]
  const float* bias  = (const float*)d_in[4];  // [256]
  float* out = (float*)d_out;

  // ws layout (~25 MB)
  char* ws = (char*)d_ws;
  size_t o = 0;
  unsigned short* Whi = (unsigned short*)(ws + o); o += 131072;
  unsigned short* Wlo = (unsigned short*)(ws + o); o += 131072;
  _Float16* XP  = (_Float16*)(ws + o); o += 8388608;
  _Float16* YPc = (_Float16*)(ws + o); o += 8388608;
  _Float16* YTc = (_Float16*)(ws + o); o += 8388608;
  int*   CIDX = (int*)  (ws + o); o += 65536;
  int*   Lc   = (int*)  (ws + o);

  prep_kernel<<<40, 256, 0, stream>>>(W, Whi, Wlo, ymask, CIDX, Lc);
  projgather_kernel<<<1536, 256, 0, stream>>>(x, y, bias, Whi, Wlo, CIDX, Lc,
                                              XP, YPc, YTc);
  flashout_kernel<<<256, 512, 0, stream>>>(XP, YPc, YTc, Lc, out);
}